// Round 1
// baseline (610.461 us; speedup 1.0000x reference)
//
#include <hip/hip_runtime.h>
#include <math.h>

// Problem constants (match reference setup_inputs)
#define NROWS   500000
#define NGRP    50000
#define D       64
#define NEG     0.2f

// d_ws layout (floats):
//   [0 .. 4095]                  Wsum = W1a + W1b + W1c   (64x64)
//   [4096 .. 4096+NGRP*64)       bias1[g][j] = -(mn_g @ W1b + mx_g @ W1c)
//   [4096+NGRP*64 .. +NROWS)     seg[row] (int32)
// total ~14.9 MB

__device__ __forceinline__ float readlane_f(float v, int k) {
    return __int_as_float(__builtin_amdgcn_readlane(__float_as_int(v), k));
}

__device__ __forceinline__ float leaky(float h) {
    return h >= 0.f ? h : NEG * h;
}

// K0: Wsum = w1[0:64] + w1[64:128] + w1[128:192]  (row-major [k][j])
__global__ void k0_wsum(const float* __restrict__ w1, float* __restrict__ wsum) {
    int i = blockIdx.x * 256 + threadIdx.x;
    if (i < 64 * 64) wsum[i] = w1[i] + w1[4096 + i] + w1[8192 + i];
}

// K1: per-group min/max + per-group bias + seg array.
// One wave per group (grid-stride). lane = feature dim.
// W1b/W1c columns live in VGPRs (128 regs); mn/mx broadcast via v_readlane.
__global__ __launch_bounds__(256, 2)
void k1_groups(const float* __restrict__ x, const int* __restrict__ csr,
               const float* __restrict__ w1, float* __restrict__ bias1,
               int* __restrict__ seg) {
    const int lane = threadIdx.x & 63;
    const int wave = blockIdx.x * (blockDim.x >> 6) + (threadIdx.x >> 6);
    const int nw   = gridDim.x * (blockDim.x >> 6);

    // column `lane` of W1b and W1c, coalesced loads (256B per instr), L2-hot
    float vb[64], vc[64];
#pragma unroll
    for (int k = 0; k < 64; ++k) {
        vb[k] = w1[(64  + k) * 64 + lane];
        vc[k] = w1[(128 + k) * 64 + lane];
    }

    for (int g = wave; g < NGRP; g += nw) {
        int p0 = csr[g], p1 = csr[g + 1];
        if (p0 >= p1) continue;  // empty group: bias never read

        float mn = INFINITY, mx = -INFINITY;
        for (int r = p0; r < p1; ++r) {
            float v = x[r * 64 + lane];
            mn = fminf(mn, v);
            mx = fmaxf(mx, v);
        }

        // element -> segment id (rows of this group are contiguous)
        for (int i = p0 + lane; i < p1; i += 64) seg[i] = g;

        // bias[lane] = -(sum_k mn[k]*W1b[k][lane] + mx[k]*W1c[k][lane])
        float b0 = 0.f, b1 = 0.f, b2 = 0.f, b3 = 0.f;
#pragma unroll
        for (int k = 0; k < 64; k += 4) {
            b0 += readlane_f(mn, k    ) * vb[k    ] + readlane_f(mx, k    ) * vc[k    ];
            b1 += readlane_f(mn, k + 1) * vb[k + 1] + readlane_f(mx, k + 1) * vc[k + 1];
            b2 += readlane_f(mn, k + 2) * vb[k + 2] + readlane_f(mx, k + 2) * vc[k + 2];
            b3 += readlane_f(mn, k + 3) * vb[k + 3] + readlane_f(mx, k + 3) * vc[k + 3];
        }
        bias1[g * 64 + lane] = -((b0 + b1) + (b2 + b3));
    }
}

// K2: MLP. One wave per 64-row tile, lane = row.
// x tile staged coalesced -> LDS (stride 65 pad => conflict-free per-k reads).
// Weights read with wave-uniform addresses -> scalar loads (SMEM pipe),
// inner loop is pure v_fmac into acc[64] VGPRs.
__global__ __launch_bounds__(64, 2)
void k2_mlp(const float* __restrict__ x, const int* __restrict__ seg,
            const float* __restrict__ bias1, const float* __restrict__ wsum,
            const float* __restrict__ w2, float* __restrict__ out) {
    __shared__ float tile[64 * 65];
    const int lane = threadIdx.x;          // 0..63
    const int row0 = blockIdx.x * 64;
    const int avail = NROWS * 64 - row0 * 64;   // floats available in tile region

    // stage 64x64 fp32 tile: coalesced float4 loads, transposed-friendly LDS layout
    const float4* x4 = (const float4*)(x + (size_t)row0 * 64);
#pragma unroll
    for (int i = 0; i < 16; ++i) {
        int f = i * 256 + lane * 4;        // flat float index in tile
        if (f < avail) {
            float4 v = x4[f >> 2];
            int r = f >> 6, c = f & 63;
            tile[r * 65 + c + 0] = v.x;
            tile[r * 65 + c + 1] = v.y;
            tile[r * 65 + c + 2] = v.z;
            tile[r * 65 + c + 3] = v.w;
        }
    }
    // single-wave block: LDS ordering handled by lgkmcnt (no barrier needed)

    const int row   = row0 + lane;
    const bool valid = row < NROWS;
    const int sg = valid ? seg[row] : 0;

    // acc[j] = bias1[seg[row]][j]  (gather; bias rows are L1/L2-hot, ~10 rows/group reuse)
    float acc[64];
#pragma unroll
    for (int j = 0; j < 64; ++j) acc[j] = valid ? bias1[sg * 64 + j] : 0.f;

    // GEMV1: acc[j] += sum_k x[row][k] * Wsum[k][j]
#pragma unroll 2
    for (int k = 0; k < 64; ++k) {
        float xk = tile[lane * 65 + k];    // conflict-free: bank (lane+k)%32
        const float* wr = wsum + k * 64;   // wave-uniform -> s_load
#pragma unroll
        for (int j = 0; j < 64; ++j) acc[j] += xk * wr[j];
    }

    // leaky + park y1 in LDS (x tile is dead; same buffer, transposed write)
#pragma unroll
    for (int j = 0; j < 64; ++j) {
        tile[lane * 65 + j] = leaky(acc[j]);   // bank (lane+j)%32: conflict-free
    }

    // GEMV2: acc2[j] = sum_k y1[row][k] * w2[k][j]
    float acc2[64];
#pragma unroll
    for (int j = 0; j < 64; ++j) acc2[j] = 0.f;
#pragma unroll 2
    for (int k = 0; k < 64; ++k) {
        float yk = tile[lane * 65 + k];
        const float* wr = w2 + k * 64;     // wave-uniform -> s_load
#pragma unroll
        for (int j = 0; j < 64; ++j) acc2[j] += yk * wr[j];
    }

    if (valid) {
        float* orow = out + (size_t)row * 64;
#pragma unroll
        for (int j = 0; j < 64; ++j) orow[j] = leaky(acc2[j]);
    }
}

extern "C" void kernel_launch(void* const* d_in, const int* in_sizes, int n_in,
                              void* d_out, int out_size, void* d_ws, size_t ws_size,
                              hipStream_t stream) {
    const float* x   = (const float*)d_in[0];
    const int*   csr = (const int*)d_in[1];
    const float* w1  = (const float*)d_in[2];
    const float* w2  = (const float*)d_in[3];
    float* out = (float*)d_out;

    float* wsum  = (float*)d_ws;
    float* bias1 = wsum + 4096;
    int*   seg   = (int*)(bias1 + (size_t)NGRP * 64);

    k0_wsum<<<16, 256, 0, stream>>>(w1, wsum);
    k1_groups<<<512, 256, 0, stream>>>(x, csr, w1, bias1, seg);
    k2_mlp<<<(NROWS + 63) / 64, 64, 0, stream>>>(x, seg, bias1, wsum, w2, out);
}